// Round 2
// baseline (446.096 us; speedup 1.0000x reference)
//
#include <hip/hip_runtime.h>

// out[b,c,n] = x[b,c, px*NY+py], px=trunc(clip(coords[b,n,1]*(NX-1),0,NX)),
//                                py=trunc(clip(coords[b,n,0]*(NY-1),0,NY))
//
// R5: R3/R4 both access xT as random 512B chunks over a 268MB span twice
// (scattered masked writes, random reads) -> ~2.5-3 TB/s HBM page-miss
// ceiling. Fix = rank-compacted staging xC[b, rank(p), c]:
//   mark:  bitmap of touched positions (as before)
//   scan:  per-batch exclusive prefix of popcounts -> base[word]
//   transpose: writes become CONTIGUOUS slabs (ranks in a p-range are
//              consecutive) -> sequential 105MB instead of scattered
//   gather: random reads land in a 13.2MB/batch compact span -> L2/L3
//           resident (x reads are nontemporal so they don't evict xC)
#define B_  8
#define C_  128
#define NX_ 256
#define NY_ 256
#define N_  32768
#define PLANE_ (NX_ * NY_)                         // 65536
#define XT_BYTES ((size_t)B_ * PLANE_ * C_ * 4)    // 268435456
#define BM_WORDS_PER_B (PLANE_ / 32)               // 2048
#define BM_BYTES ((size_t)B_ * BM_WORDS_PER_B * 4) // 65536
#define WS_NEED (XT_BYTES + 2 * BM_BYTES)

typedef float f32x4 __attribute__((ext_vector_type(4)));
typedef float f32x2 __attribute__((ext_vector_type(2)));

__device__ __forceinline__ int sample_idx(const float* __restrict__ coords, int b, int n) {
    const float2 cc = *reinterpret_cast<const float2*>(coords + ((size_t)b * N_ + n) * 2);
    const int px = (int)fminf(fmaxf(cc.y * (float)(NX_ - 1), 0.0f), (float)NX_);
    const int py = (int)fminf(fmaxf(cc.x * (float)(NY_ - 1), 0.0f), (float)NY_);
    return min(px * NY_ + py, PLANE_ - 1);
}

// ---- pass 0: mark touched positions ---------------------------------------
__global__ __launch_bounds__(256) void mark_kernel(const float* __restrict__ coords,
                                                   unsigned* __restrict__ bm) {
    const int n = blockIdx.x * 256 + threadIdx.x;
    const int b = blockIdx.y;
    const int idx = sample_idx(coords, b, n);
    atomicOr(&bm[b * BM_WORDS_PER_B + (idx >> 5)], 1u << (idx & 31));
}

// ---- pass 0.5: per-batch exclusive prefix of per-word popcounts -----------
__global__ __launch_bounds__(256) void scan_kernel(const unsigned* __restrict__ bm,
                                                   unsigned* __restrict__ base) {
    __shared__ unsigned ts[256];
    const int b = blockIdx.x, t = threadIdx.x;
    const unsigned* __restrict__ w = bm + b * BM_WORDS_PER_B + t * 8;
    unsigned c[8], s = 0;
    #pragma unroll
    for (int j = 0; j < 8; ++j) { c[j] = s; s += __popc(w[j]); }
    ts[t] = s;
    __syncthreads();
    #pragma unroll
    for (int off = 1; off < 256; off <<= 1) {        // inclusive scan
        const unsigned v = (t >= off) ? ts[t - off] : 0u;
        __syncthreads();
        ts[t] += v;
        __syncthreads();
    }
    const unsigned pre = ts[t] - s;                  // exclusive thread prefix
    unsigned* __restrict__ o = base + b * BM_WORDS_PER_B + t * 8;
    #pragma unroll
    for (int j = 0; j < 8; ++j) o[j] = pre + c[j];
}

// ---- pass 1: transpose (b,c,p) -> compacted (b,rank,c) --------------------
// 128 positions x 128 channels per block. Reads: 512B float4 nontemporal.
// Writes: contiguous rank-ordered slab (~25KB sequential per block).
__global__ __launch_bounds__(256, 2) void transpose_kernel(const float* __restrict__ x,
                                                           const unsigned* __restrict__ bm,
                                                           const unsigned* __restrict__ base,
                                                           float* __restrict__ xC) {
    __shared__ float tile[128][130];
    const int bid = blockIdx.x;
    const int b   = bid & 7;                     // XCD spread / batch affinity
    const int p0  = (bid >> 3) << 7;             // 128 positions per block
    const int t   = threadIdx.x;
    const int w   = t >> 6, l = t & 63;
    const int q   = l & 31, h = l >> 5;

    const float* __restrict__ xb = x + (size_t)b * C_ * PLANE_ + p0;
    #pragma unroll
    for (int r = 0; r < 16; ++r) {
        const int c = r * 8 + w * 2 + h;
        const f32x4 v = __builtin_nontemporal_load(
            reinterpret_cast<const f32x4*>(xb + (size_t)c * PLANE_ + 4 * q));
        #pragma unroll
        for (int j = 0; j < 4; ++j) tile[4 * q + j][c] = v[j];
    }
    __syncthreads();

    float* __restrict__ xCb = xC + (size_t)b * PLANE_ * C_;
    const unsigned* __restrict__ bmb = bm + b * BM_WORDS_PER_B;
    const unsigned* __restrict__ bsb = base + b * BM_WORDS_PER_B;
    #pragma unroll
    for (int r = 0; r < 32; ++r) {
        const int p  = r * 4 + w;                // wave-uniform -> uniform branch
        const int gp = p0 + p;
        const unsigned bits = bmb[gp >> 5];
        if (bits & (1u << (gp & 31))) {
            const unsigned rank = bsb[gp >> 5] + __popc(bits & ((1u << (gp & 31)) - 1u));
            const f32x2 v2 = *reinterpret_cast<const f32x2*>(&tile[p][2 * l]);
            *reinterpret_cast<f32x2*>(&xCb[(size_t)rank * C_ + 2 * l]) = v2;
        }
    }
}

// ---- pass 2: gather 128 samples x 128 channels per block ------------------
// Reads: 512B/sample from the 13.2MB/batch compact span (L2/L3 resident).
// Stores: 512B float2 nontemporal per channel row.
__global__ __launch_bounds__(256, 2) void gather_kernel(const float* __restrict__ xC,
                                                        const unsigned* __restrict__ bm,
                                                        const unsigned* __restrict__ base,
                                                        const float* __restrict__ coords,
                                                        float* __restrict__ out) {
    __shared__ float smp[C_][130];
    __shared__ int   sidx[128];
    const int bid = blockIdx.x;
    const int b   = bid & 7;                     // XCD-affine batch
    const int n0  = (bid >> 3) << 7;             // 128 samples per block
    const int t   = threadIdx.x;
    const int w   = t >> 6, l = t & 63;
    const int cq  = l & 31, sh = l >> 5;

    if (t < 128) {
        const int idx = sample_idx(coords, b, n0 + t);
        const unsigned bits = bm[b * BM_WORDS_PER_B + (idx >> 5)];
        sidx[t] = (int)(base[b * BM_WORDS_PER_B + (idx >> 5)] +
                        __popc(bits & ((1u << (idx & 31)) - 1u)));
    }
    __syncthreads();

    const float* __restrict__ xCb = xC + (size_t)b * PLANE_ * C_;
    #pragma unroll
    for (int r = 0; r < 16; ++r) {               // s = 0..127
        const int s = r * 8 + w * 2 + sh;
        const f32x4 v = *reinterpret_cast<const f32x4*>(xCb + (size_t)sidx[s] * C_ + 4 * cq);
        #pragma unroll
        for (int j = 0; j < 4; ++j) smp[4 * cq + j][s] = v[j];
    }
    __syncthreads();

    float* __restrict__ ob = out + (size_t)b * C_ * N_ + n0;
    #pragma unroll
    for (int r = 0; r < 32; ++r) {               // c = 0..127
        const int c = r * 4 + w;
        const f32x2 v2 = *reinterpret_cast<const f32x2*>(&smp[c][2 * l]);
        __builtin_nontemporal_store(v2, reinterpret_cast<f32x2*>(ob + (size_t)c * N_ + 2 * l));
    }
}

// ---- fallback (R2): direct gather, used only if ws too small --------------
__global__ __launch_bounds__(256) void fallback_kernel(const float* __restrict__ x,
                                                       const float* __restrict__ coords,
                                                       float* __restrict__ out) {
    const int bid  = blockIdx.x;
    const int b    = bid & 7;
    const int rem  = bid >> 3;
    const int cg   = rem >> 7;
    const int nblk = rem & 127;
    const int n  = nblk * 256 + threadIdx.x;
    const int c0 = cg * 8;
    const int idx = sample_idx(coords, b, n);
    const float* __restrict__ xb = x + ((size_t)b * C_ + c0) * PLANE_ + idx;
    float* __restrict__ ob = out + ((size_t)b * C_ + c0) * N_ + n;
    #pragma unroll
    for (int i = 0; i < 8; ++i)
        __builtin_nontemporal_store(xb[(size_t)i * PLANE_], ob + (size_t)i * N_);
}

extern "C" void kernel_launch(void* const* d_in, const int* in_sizes, int n_in,
                              void* d_out, int out_size, void* d_ws, size_t ws_size,
                              hipStream_t stream) {
    const float* x      = (const float*)d_in[0];
    const float* coords = (const float*)d_in[1];
    float* out          = (float*)d_out;

    if (ws_size >= WS_NEED) {
        float*    xC   = (float*)d_ws;
        unsigned* bm   = (unsigned*)((char*)d_ws + XT_BYTES);
        unsigned* base = (unsigned*)((char*)d_ws + XT_BYTES + BM_BYTES);
        hipMemsetAsync(bm, 0, BM_BYTES, stream);
        mark_kernel<<<dim3(N_ / 256, B_), 256, 0, stream>>>(coords, bm);
        scan_kernel<<<B_, 256, 0, stream>>>(bm, base);
        transpose_kernel<<<B_ * (PLANE_ / 128), 256, 0, stream>>>(x, bm, base, xC);
        gather_kernel<<<B_ * (N_ / 128), 256, 0, stream>>>(xC, bm, base, coords, out);
    } else {
        fallback_kernel<<<B_ * 16 * 128, 256, 0, stream>>>(x, coords, out);
    }
}